// Round 7
// baseline (378.041 us; speedup 1.0000x reference)
//
#include <hip/hip_runtime.h>

typedef __bf16 bf16_t;
typedef __bf16 bf16x8 __attribute__((ext_vector_type(8)));
typedef __bf16 bf16x4 __attribute__((ext_vector_type(4)));
typedef __bf16 bf16x2 __attribute__((ext_vector_type(2)));
typedef float  f32x4  __attribute__((ext_vector_type(4)));
typedef float  f32x16 __attribute__((ext_vector_type(16)));
typedef unsigned int u32x4 __attribute__((ext_vector_type(4)));
typedef int i32x2 __attribute__((ext_vector_type(2)));

#define MFMA16(A, B, C) __builtin_amdgcn_mfma_f32_16x16x32_bf16((A), (B), (C), 0, 0, 0)
#define MFMA32(A, B, C) __builtin_amdgcn_mfma_f32_32x32x16_bf16((A), (B), (C), 0, 0, 0)

constexpr int BB = 4;
constexpr int SS = 2048;
constexpr int DD = 1024;
constexpr int HH = 16;
constexpr int DH = 64;
// p = exp2(score * SCALE * log2(e) - vml*log2(e)); SCALE = 1/8
constexpr float C1 = 0.18033688011112042f;   // 0.125 * log2(e)
constexpr float C2 = 1.4426950408889634e10f; // 1e10 * log2(e)

// async global->LDS. LDS dest = wave-uniform base + lane*size.
__device__ __forceinline__ void async_copy16(const void* g, void* l) {
    __builtin_amdgcn_global_load_lds(
        (const __attribute__((address_space(1))) void*)g,
        (__attribute__((address_space(3))) void*)l, 16, 0, 0);
}
__device__ __forceinline__ void async_copy4(const void* g, void* l) {
    __builtin_amdgcn_global_load_lds(
        (const __attribute__((address_space(1))) void*)g,
        (__attribute__((address_space(3))) void*)l, 4, 0, 0);
}

// counted-vmcnt phase sync (T4): retire exactly the previous tile's load
// group; the just-issued group stays in flight across the barrier.
#define PHASE_SYNC(N) do {                                          \
    asm volatile("s_waitcnt vmcnt(" #N ")" ::: "memory");           \
    __builtin_amdgcn_s_barrier();                                   \
    __builtin_amdgcn_sched_barrier(0);                              \
} while (0)

// pack two f32 into one u32 of 2 bf16 (compiler emits v_cvt_pk)
__device__ __forceinline__ unsigned pack_bf16(float lo, float hi) {
    bf16x2 t;
    t[0] = (bf16_t)lo;
    t[1] = (bf16_t)hi;
    return __builtin_bit_cast(unsigned, t);
}

// v_permlane32_swap_b32: a = {a.lo32, b.lo32}, b = {a.hi32, b.hi32}
__device__ __forceinline__ void permswap(unsigned& a, unsigned& b) {
    i32x2 r = __builtin_amdgcn_permlane32_swap((int)a, (int)b, false, false);
    a = (unsigned)r[0];
    b = (unsigned)r[1];
}

// pack a 32-key P column slice (post-softmax st) into the two 16-key
// B-operand fragments for PV (T12 pairing; verified rounds 0-6).
__device__ __forceinline__ void packP(const f32x16& st, bf16x8& w0, bf16x8& w1) {
    unsigned a0 = pack_bf16(st[0],  st[1]);
    unsigned a1 = pack_bf16(st[2],  st[3]);
    unsigned a2 = pack_bf16(st[4],  st[5]);
    unsigned a3 = pack_bf16(st[6],  st[7]);
    unsigned a4 = pack_bf16(st[8],  st[9]);
    unsigned a5 = pack_bf16(st[10], st[11]);
    unsigned a6 = pack_bf16(st[12], st[13]);
    unsigned a7 = pack_bf16(st[14], st[15]);
    permswap(a0, a2);
    permswap(a1, a3);
    permswap(a4, a6);
    permswap(a5, a7);
    u32x4 u0 = {a0, a1, a2, a3};   // keys [0,16) of the 32-key window
    u32x4 u1 = {a4, a5, a6, a7};   // keys [16,32)
    w0 = __builtin_bit_cast(bf16x8, u0);
    w1 = __builtin_bit_cast(bf16x8, u1);
}

// ---------------------------------------------------------------------------
// fp32 -> bf16 conversion of q,k,v inputs. grid (4096,1,3), block 256.
// ---------------------------------------------------------------------------
__global__ __launch_bounds__(256) void conv_kernel(
    const float* __restrict__ q, const float* __restrict__ k,
    const float* __restrict__ v, bf16_t* __restrict__ outb)
{
    const float* src = blockIdx.z == 0 ? q : blockIdx.z == 1 ? k : v;
    bf16_t* dst = outb + ((size_t)blockIdx.z << 23);
    size_t i = ((size_t)blockIdx.x * 256 + threadIdx.x) * 8;
    f32x4 a = *(const f32x4*)&src[i];
    f32x4 b = *(const f32x4*)&src[i + 4];
    bf16x8 o;
    o[0] = (bf16_t)a[0]; o[1] = (bf16_t)a[1]; o[2] = (bf16_t)a[2]; o[3] = (bf16_t)a[3];
    o[4] = (bf16_t)b[0]; o[5] = (bf16_t)b[1]; o[6] = (bf16_t)b[2]; o[7] = (bf16_t)b[3];
    *(bf16x8*)&dst[i] = o;
}

// ---------------------------------------------------------------------------
// transpose + convert weights: W[k][n] fp32 -> Wt[n][k] bf16. grid (16,16,3).
// ---------------------------------------------------------------------------
__global__ __launch_bounds__(256) void wtrans_kernel(
    const float* __restrict__ Wq, const float* __restrict__ Wk,
    const float* __restrict__ Wv, bf16_t* __restrict__ Wt)
{
    const float* W = blockIdx.z == 0 ? Wq : blockIdx.z == 1 ? Wk : Wv;
    bf16_t* T = Wt + ((size_t)blockIdx.z << 20);

    __shared__ __align__(16) bf16_t tile[64][72];

    const int k0 = blockIdx.x * 64;
    const int n0 = blockIdx.y * 64;
    const int tid = threadIdx.x;

    #pragma unroll
    for (int i = 0; i < 4; i++) {
        int idx = tid + i * 256;
        int kk = idx >> 4;
        int nn = (idx & 15) * 4;
        f32x4 w = *(const f32x4*)&W[(size_t)(k0 + kk) * 1024 + n0 + nn];
        tile[nn + 0][kk] = (bf16_t)w[0];
        tile[nn + 1][kk] = (bf16_t)w[1];
        tile[nn + 2][kk] = (bf16_t)w[2];
        tile[nn + 3][kk] = (bf16_t)w[3];
    }
    __syncthreads();
    #pragma unroll
    for (int i = 0; i < 2; i++) {
        int idx = tid + i * 256;
        int nn = idx >> 3;
        int kk = (idx & 7) * 8;
        *(bf16x8*)&T[(size_t)(n0 + nn) * 1024 + k0 + kk] =
            *(const bf16x8*)&tile[nn][kk];
    }
}

// ---------------------------------------------------------------------------
// projection GEMM: C = Ab(bf16)[8192x1024] @ Wt^T -> bf16. BK=64.
// grid (512, 1, 3), block 256: 4 waves, each 64x64 of the 128x128 tile.
// ---------------------------------------------------------------------------
__global__ __launch_bounds__(256) void proj_kernel(
    const bf16_t* __restrict__ Ab, const bf16_t* __restrict__ Wt,
    bf16_t* __restrict__ qw, bf16_t* __restrict__ kw, bf16_t* __restrict__ vwt)
{
    const int which = blockIdx.z;
    const bf16_t* A = Ab + ((size_t)which << 23);
    const bf16_t* T = Wt + ((size_t)which << 20);

    __shared__ bf16_t Alds[128 * 64];  // [row][64k], 16B chunk c at c^(row&7)
    __shared__ bf16_t Blds[128 * 64];

    const int tid = threadIdx.x;
    const int lane = tid & 63;
    const int wave = tid >> 6;
    const int quad = lane >> 4;
    const int l16 = lane & 15;

    // XCD-locality decode: presumed placement XCD = blockIdx.x % 8
    const int id = blockIdx.x;
    const int xg = id & 7;
    const int sl = id >> 3;                   // 0..63
    const int m0 = (((xg << 3) | (sl >> 3))) * 128;  // XCD xg: m-panels xg*8..xg*8+7
    const int n0 = (sl & 7) * 128;

    const int wm = (wave >> 1) * 64;
    const int wn = (wave & 1) * 64;

    const int srow = lane >> 3;   // 8 rows per staging instr
    const int schk = lane & 7;    // physical 16B chunk

    f32x4 zero4 = {0.f, 0.f, 0.f, 0.f};
    f32x4 acc[4][4];
    #pragma unroll
    for (int i = 0; i < 4; i++)
        #pragma unroll
        for (int j = 0; j < 4; j++) acc[i][j] = zero4;

    for (int k0 = 0; k0 < DD; k0 += 64) {
        #pragma unroll
        for (int j = 0; j < 4; j++) {
            int r0 = wave * 32 + j * 8;
            int row = r0 + srow;
            int c = schk ^ (row & 7);
            async_copy16(&A[(size_t)(m0 + row) * 1024 + k0 + c * 8], &Alds[r0 * 64]);
        }
        #pragma unroll
        for (int j = 0; j < 4; j++) {
            int r0 = wave * 32 + j * 8;
            int row = r0 + srow;
            int c = schk ^ (row & 7);
            async_copy16(&T[(size_t)(n0 + row) * 1024 + k0 + c * 8], &Blds[r0 * 64]);
        }
        __syncthreads();

        #pragma unroll
        for (int s = 0; s < 2; s++) {
            bf16x8 af[4], bfr[4];
            #pragma unroll
            for (int mi = 0; mi < 4; mi++)
                af[mi] = *(const bf16x8*)&Alds[(wm + mi * 16 + l16) * 64 +
                             (((s * 4 + quad) ^ (l16 & 7)) << 3)];
            #pragma unroll
            for (int ni = 0; ni < 4; ni++)
                bfr[ni] = *(const bf16x8*)&Blds[(wn + ni * 16 + l16) * 64 +
                              (((s * 4 + quad) ^ (l16 & 7)) << 3)];
            #pragma unroll
            for (int mi = 0; mi < 4; mi++)
                #pragma unroll
                for (int ni = 0; ni < 4; ni++)
                    acc[mi][ni] = MFMA16(af[mi], bfr[ni], acc[mi][ni]);
        }
        __syncthreads();
    }

    // C/D layout: col=lane&15, row=quad*4+reg
    if (which < 2) {
        bf16_t* Cout = which == 0 ? qw : kw;
        #pragma unroll
        for (int mi = 0; mi < 4; mi++)
            #pragma unroll
            for (int ni = 0; ni < 4; ni++)
                #pragma unroll
                for (int r = 0; r < 4; r++) {
                    int row = m0 + wm + mi * 16 + quad * 4 + r;
                    int col = n0 + wn + ni * 16 + l16;
                    Cout[(size_t)row * 1024 + col] = (bf16_t)acc[mi][ni][r];
                }
    } else {
        // vwt[b][h][d][s]; the 4 acc regs are s-consecutive -> bf16x4 stores
        #pragma unroll
        for (int mi = 0; mi < 4; mi++)
            #pragma unroll
            for (int ni = 0; ni < 4; ni++) {
                int s0 = m0 + wm + mi * 16 + quad * 4;
                int col = n0 + wn + ni * 16 + l16;
                int b = s0 >> 11, s = s0 & 2047;
                int h = col >> 6, d = col & 63;
                bf16x4 p;
                p[0] = (bf16_t)acc[mi][ni][0]; p[1] = (bf16_t)acc[mi][ni][1];
                p[2] = (bf16_t)acc[mi][ni][2]; p[3] = (bf16_t)acc[mi][ni][3];
                *(bf16x4*)&vwt[(((size_t)((b * HH + h) * DH + d)) << 11) + s] = p;
            }
    }
}

// ---------------------------------------------------------------------------
// flash attention, 32x32 swapped-operand, no-rescale softmax, KEY-SPLIT waves
// (= round-5 kernel) + T3/T4 counted-vmcnt phase pipeline.
// Evidence R1/R2/R5: duration invariant under halved VALU and halved LDS
// reads, MfmaUtil pinned 24%, no pipe >50% -> the stage->drain->barrier
// serialization is the cost (m233's 72%-overhead signature). Fix (m218):
// never drain vmcnt to 0 in the loop. Per tile, per wave, exactly 5 VMEM
// ops in two groups: P1{K:2 + vml:1} and P2{V:2}; each phase issues its
// next-tile group, then waits vmcnt(5) = retire previous tile's group
// while this tile's 5 stay in flight (a full tile of lead). Tail keeps the
// count uniform by re-issuing tile 31's loads (in-bounds, dead buffer);
// one vmcnt(0 ) before the epilogue reduction.
// grid (1024, 1, 1), block 256 (4 waves: 2 q-groups x 2 key-halves).
// ---------------------------------------------------------------------------
__global__ __launch_bounds__(256) void attn_kernel(
    const bf16_t* __restrict__ qw, const bf16_t* __restrict__ kw,
    const bf16_t* __restrict__ vwt, const float* __restrict__ v_mask,
    const float* __restrict__ q_mask, float* __restrict__ out)
{
    // XCD-locality decode
    const int linear = blockIdx.x;           // 0..1023
    const int xg = linear & 7;               // presumed XCD
    const int sl = linear >> 3;              // 0..127
    const int grp = (xg << 3) | (sl >> 4);   // 0..63: XCD xg gets groups xg*8..+7
    const int qt = sl & 15;
    const int b = grp >> 4;
    const int h = grp & 15;

    // K bufs at 0 / 4096 el, V^T bufs at 8192 / 12288 el (each 64x64 bf16)
    __shared__ __align__(16) bf16_t KV[4 * 4096];
    __shared__ float vml[2][64];             // raw v_mask staged per tile
    __shared__ float lred[2][2][64];         // [qg][qb][lane] l partials

    const int tid = threadIdx.x;
    const int lane = tid & 63;
    const int wave = tid >> 6;
    const int qg = wave >> 1;                // q-group 0/1 (64 queries each)
    const int kh = wave & 1;                 // key-half 0/1 (32 keys of 64)
    const int l5 = lane & 31;
    const int hi = lane >> 5;
    const int q0 = qt * 128 + qg * 64;

    const int srow = lane >> 3;   // staging: 8 rows per instr
    const int schk = lane & 7;    // physical 16B chunk
    const int ck = schk ^ srow;

    // Q fragments: B-operand; qf[qb][c]: query q0+qb*32+l5, d = c*16+hi*8..+7
    bf16x8 qf[2][4];
    #pragma unroll
    for (int qb = 0; qb < 2; ++qb)
        #pragma unroll
        for (int c = 0; c < 4; ++c)
            qf[qb][c] = *(const bf16x8*)&qw[(size_t)(b * SS + q0 + qb * 32 + l5) * 1024 +
                                            h * 64 + c * 16 + hi * 8];

    f32x16 zero16;
    #pragma unroll
    for (int i = 0; i < 16; ++i) zero16[i] = 0.f;

    // loop-invariant LDS read pointers (physical chunk = logical ^ (row&7)):
    // K (c-th 16-d chunk of row kh*32+l5):  chunk = (2c+hi)^(l5&7) = vkh^2c
    // V (ks-th 16-key chunk of row db*32+l5): chunk = vkh ^ 4*kh ^ 2*ks
    const int vkh = (l5 & 7) ^ hi;
    const bf16_t* pk[4];
    #pragma unroll
    for (int c = 0; c < 4; ++c)
        pk[c] = &KV[kh * 2048 + l5 * 64 + ((vkh ^ (2 * c)) << 3)];
    const bf16_t* pv[2];
    #pragma unroll
    for (int ks = 0; ks < 2; ++ks)
        pv[ks] = &KV[8192 + l5 * 64 + ((vkh ^ (4 * kh) ^ (2 * ks)) << 3)];
    const float* vmlp = &vml[0][kh * 32 + hi * 4];   // LDS softmax-mask base

    // persistent staging pointers
    const bf16_t* gk = &kw[(size_t)(b * SS + wave * 16 + srow) * 1024 + h * 64 + ck * 8];
    const bf16_t* gv = &vwt[(((size_t)((b * HH + h) * DH + wave * 16 + srow)) << 11) +
                            ck * 8];
    const float* vsrc = v_mask + b * SS + lane;

    // per-phase stage groups (uniform 3 + 2 VMEM ops per wave per tile)
    auto stageK = [&](int bi) {   // K rows wave*16..+15 + whole-tile v_mask
        async_copy16(gk,        &KV[bi * 4096 + (wave * 16) * 64]);
        async_copy16(gk + 8192, &KV[bi * 4096 + (wave * 16 + 8) * 64]);
        async_copy4(vsrc, &vml[bi][0]);   // all 4 waves: identical data, benign
    };
    auto stageV = [&](int bi) {   // V^T d-rows wave*16..+15
        async_copy16(gv,         &KV[8192 + bi * 4096 + (wave * 16) * 64]);
        async_copy16(gv + 16384, &KV[8192 + bi * 4096 + (wave * 16 + 8) * 64]);
    };

    // prologue: tile 0 into buf 0; queue = 5
    stageK(0);
    stageV(0);
    gk += 65536; gv += 64; vsrc += 64;   // -> tile 1

    // O^T accumulators per (qb, db); l partial chains
    f32x16 o00 = zero16, o01 = zero16, o10 = zero16, o11 = zero16;
    f32x4 la = {0.f, 0.f, 0.f, 0.f};
    f32x4 lb = {0.f, 0.f, 0.f, 0.f};

    for (int t2 = 0; t2 < 32; t2 += 2) {
        #pragma unroll
        for (int cur = 0; cur < 2; ++cur) {
            const int cb = cur * 4096;
            const bool adv = (t2 + cur) < 30;   // stop advancing at tile 31

            // ---------------- P1: K-phase ----------------
            stageK(cur ^ 1);                 // issue K(t+1) group (3 ops)
            if (adv) { gk += 65536; vsrc += 64; }
            PHASE_SYNC(5);                   // retire K(t)+vml(t); keep 5 in flight

            __builtin_amdgcn_s_setprio(1);
            f32x16 st0, st1;
            {
                bf16x8 kf = *(const bf16x8*)(pk[0] + cb);
                st0 = MFMA32(kf, qf[0][0], zero16);
                st1 = MFMA32(kf, qf[1][0], zero16);
            }
            #pragma unroll
            for (int c = 1; c < 4; ++c) {
                bf16x8 kf = *(const bf16x8*)(pk[c] + cb);
                st0 = MFMA32(kf, qf[0][c], st0);
                st1 = MFMA32(kf, qf[1][c], st1);
            }
            __builtin_amdgcn_s_setprio(0);

            // softmax: p = exp2(s*C1 + (vm*C2 - C2)); vm from LDS (broadcast)
            #pragma unroll
            for (int g = 0; g < 4; ++g) {
                f32x4 vm4 = *(const f32x4*)(vmlp + cur * 64 + g * 8);
                #pragma unroll
                for (int j = 0; j < 4; ++j) {
                    float nv = __builtin_fmaf(vm4[j], C2, -C2);
                    float p0 = __builtin_amdgcn_exp2f(
                        __builtin_fmaf(st0[g * 4 + j], C1, nv));
                    st0[g * 4 + j] = p0;
                    la[j] += p0;
                    float p1 = __builtin_amdgcn_exp2f(
                        __builtin_fmaf(st1[g * 4 + j], C1, nv));
                    st1[g * 4 + j] = p1;
                    lb[j] += p1;
                }
            }

            // pack P -> PV B-operands (per q-block, two 16-key fragments)
            bf16x8 bp00, bp01, bp10, bp11;
            packP(st0, bp00, bp01);
            packP(st1, bp10, bp11);

            // ---------------- P2: V-phase ----------------
            stageV(cur ^ 1);                 // issue V(t+1) group (2 ops)
            if (adv) gv += 64;
            PHASE_SYNC(5);                   // retire V(t); keep 5 in flight

            __builtin_amdgcn_s_setprio(1);
            #pragma unroll
            for (int ks = 0; ks < 2; ++ks) {
                bf16x8 bpa = ks ? bp01 : bp00;
                bf16x8 bpb = ks ? bp11 : bp10;
                bf16x8 av0 = *(const bf16x8*)(pv[ks] + cb);
                bf16x8 av1 = *(const bf16x8*)(pv[ks] + cb + 2048);
                o00 = MFMA32(av0, bpa, o00);
                o10 = MFMA32(av0, bpb, o10);
                o01 = MFMA32(av1, bpa, o01);
                o11 = MFMA32(av1, bpb, o11);
            }
            __builtin_amdgcn_s_setprio(0);
        }
    }

    // drain the redundant tail loads before reusing KV as reduction scratch
    asm volatile("s_waitcnt vmcnt(0)" ::: "memory");
    __syncthreads();

    // ---- cross key-half reduction (through LDS) ----
    float ls0 = (la[0] + la[1]) + (la[2] + la[3]);
    float ls1 = (lb[0] + lb[1]) + (lb[2] + lb[3]);
    float* R = (float*)KV;

    if (kh == 1) {
        *(f32x16*)&R[((qg * 2 + 0) * 2 + 0) * 1024 + lane * 16] = o00;
        *(f32x16*)&R[((qg * 2 + 0) * 2 + 1) * 1024 + lane * 16] = o01;
        *(f32x16*)&R[((qg * 2 + 1) * 2 + 0) * 1024 + lane * 16] = o10;
        *(f32x16*)&R[((qg * 2 + 1) * 2 + 1) * 1024 + lane * 16] = o11;
        lred[qg][0][lane] = ls0;
        lred[qg][1][lane] = ls1;
    }
    __syncthreads();
    if (kh == 0) {
        o00 += *(const f32x16*)&R[((qg * 2 + 0) * 2 + 0) * 1024 + lane * 16];
        o01 += *(const f32x16*)&R[((qg * 2 + 0) * 2 + 1) * 1024 + lane * 16];
        o10 += *(const f32x16*)&R[((qg * 2 + 1) * 2 + 0) * 1024 + lane * 16];
        o11 += *(const f32x16*)&R[((qg * 2 + 1) * 2 + 1) * 1024 + lane * 16];
        ls0 += lred[qg][0][lane];
        ls1 += lred[qg][1][lane];
        // combine the two hi halves (keys split by 4*hi)
        ls0 += __shfl_xor(ls0, 32);
        ls1 += __shfl_xor(ls1, 32);

        const float sc0 = q_mask[b * SS + q0 + l5] / ls0;
        const float sc1 = q_mask[b * SS + q0 + 32 + l5] / ls1;

        // O^T reg r: d = db*32 + (r&3) + 8*(r>>2) + 4*hi, query = q0+qb*32+l5
        #pragma unroll
        for (int qb = 0; qb < 2; ++qb) {
            const float sc = qb ? sc1 : sc0;
            const int q = q0 + qb * 32 + l5;
            #pragma unroll
            for (int db = 0; db < 2; ++db) {
                const f32x16 oa = qb ? (db ? o11 : o10) : (db ? o01 : o00);
                #pragma unroll
                for (int g = 0; g < 4; ++g) {
                    f32x4 o4;
                    o4[0] = oa[g * 4 + 0] * sc;
                    o4[1] = oa[g * 4 + 1] * sc;
                    o4[2] = oa[g * 4 + 2] * sc;
                    o4[3] = oa[g * 4 + 3] * sc;
                    *(f32x4*)&out[(size_t)(b * SS + q) * 1024 + h * 64 +
                                  db * 32 + g * 8 + hi * 4] = o4;
                }
            }
        }
    }
}

// ---------------------------------------------------------------------------
extern "C" void kernel_launch(void* const* d_in, const int* in_sizes, int n_in,
                              void* d_out, int out_size, void* d_ws, size_t ws_size,
                              hipStream_t stream)
{
    const float* q  = (const float*)d_in[0];
    const float* k  = (const float*)d_in[1];
    const float* v  = (const float*)d_in[2];
    const float* vm = (const float*)d_in[3];
    const float* qm = (const float*)d_in[4];
    const float* Wq = (const float*)d_in[5];
    const float* Wk = (const float*)d_in[6];
    const float* Wv = (const float*)d_in[7];
    float* out = (float*)d_out;

    const size_t elems = (size_t)BB * SS * DD;  // 8388608
    bf16_t* Ab  = (bf16_t*)d_ws;       // qb,kb,vb: 3*elems
    bf16_t* qw  = Ab + 3 * elems;
    bf16_t* kw  = qw + elems;
    bf16_t* vwt = kw + elems;
    bf16_t* Wt  = vwt + elems;         // 3 x 1024 x 1024

    conv_kernel<<<dim3(4096, 1, 3), 256, 0, stream>>>(q, k, v, Ab);
    wtrans_kernel<<<dim3(16, 16, 3), 256, 0, stream>>>(Wq, Wk, Wv, Wt);
    proj_kernel<<<dim3(512, 1, 3), 256, 0, stream>>>(Ab, Wt, qw, kw, vwt);
    attn_kernel<<<dim3(1024, 1, 1), 256, 0, stream>>>(qw, kw, vwt, vm, qm, out);
}

// Round 8
// 325.139 us; speedup vs baseline: 1.1627x; 1.1627x over previous
//
#include <hip/hip_runtime.h>

typedef __bf16 bf16_t;
typedef __bf16 bf16x8 __attribute__((ext_vector_type(8)));
typedef __bf16 bf16x4 __attribute__((ext_vector_type(4)));
typedef __bf16 bf16x2 __attribute__((ext_vector_type(2)));
typedef float  f32x4  __attribute__((ext_vector_type(4)));
typedef float  f32x16 __attribute__((ext_vector_type(16)));
typedef unsigned int u32x4 __attribute__((ext_vector_type(4)));
typedef int i32x2 __attribute__((ext_vector_type(2)));

#define MFMA16(A, B, C) __builtin_amdgcn_mfma_f32_16x16x32_bf16((A), (B), (C), 0, 0, 0)
#define MFMA32(A, B, C) __builtin_amdgcn_mfma_f32_32x32x16_bf16((A), (B), (C), 0, 0, 0)

constexpr int BB = 4;
constexpr int SS = 2048;
constexpr int DD = 1024;
constexpr int HH = 16;
constexpr int DH = 64;
// p = exp2(score * SCALE * log2(e) - vml*log2(e)); SCALE = 1/8
constexpr float C1 = 0.18033688011112042f;   // 0.125 * log2(e)

// async global->LDS, 16B per lane. LDS dest = wave-uniform base + lane*16.
__device__ __forceinline__ void async_copy16(const void* g, void* l) {
    __builtin_amdgcn_global_load_lds(
        (const __attribute__((address_space(1))) void*)g,
        (__attribute__((address_space(3))) void*)l, 16, 0, 0);
}

// pack two f32 into one u32 of 2 bf16 (compiler emits v_cvt_pk)
__device__ __forceinline__ unsigned pack_bf16(float lo, float hi) {
    bf16x2 t;
    t[0] = (bf16_t)lo;
    t[1] = (bf16_t)hi;
    return __builtin_bit_cast(unsigned, t);
}

// v_permlane32_swap_b32: a = {a.lo32, b.lo32}, b = {a.hi32, b.hi32}
__device__ __forceinline__ void permswap(unsigned& a, unsigned& b) {
    i32x2 r = __builtin_amdgcn_permlane32_swap((int)a, (int)b, false, false);
    a = (unsigned)r[0];
    b = (unsigned)r[1];
}

// ---------------------------------------------------------------------------
// transpose + convert weights: W[k][n] fp32 -> Wt[n][k] bf16. grid (16,16,3).
// ---------------------------------------------------------------------------
__global__ __launch_bounds__(256) void wtrans_kernel(
    const float* __restrict__ Wq, const float* __restrict__ Wk,
    const float* __restrict__ Wv, bf16_t* __restrict__ Wt)
{
    const float* W = blockIdx.z == 0 ? Wq : blockIdx.z == 1 ? Wk : Wv;
    bf16_t* T = Wt + ((size_t)blockIdx.z << 20);

    __shared__ __align__(16) bf16_t tile[64][72];

    const int k0 = blockIdx.x * 64;
    const int n0 = blockIdx.y * 64;
    const int tid = threadIdx.x;

    #pragma unroll
    for (int i = 0; i < 4; i++) {
        int idx = tid + i * 256;
        int kk = idx >> 4;
        int nn = (idx & 15) * 4;
        f32x4 w = *(const f32x4*)&W[(size_t)(k0 + kk) * 1024 + n0 + nn];
        tile[nn + 0][kk] = (bf16_t)w[0];
        tile[nn + 1][kk] = (bf16_t)w[1];
        tile[nn + 2][kk] = (bf16_t)w[2];
        tile[nn + 3][kk] = (bf16_t)w[3];
    }
    __syncthreads();
    #pragma unroll
    for (int i = 0; i < 2; i++) {
        int idx = tid + i * 256;
        int nn = idx >> 3;
        int kk = (idx & 7) * 8;
        *(bf16x8*)&T[(size_t)(n0 + nn) * 1024 + k0 + kk] =
            *(const bf16x8*)&tile[nn][kk];
    }
}

// ---------------------------------------------------------------------------
// projection GEMM with FUSED fp32->bf16 conversion of A (conv_kernel
// deleted): C = A(fp32,[8192x1024]) @ Wt^T -> bf16. BK=64.
// A is reg-staged: per lane 2x global_load_dwordx4 (fp32) + cvt + one
// lane-linear ds_write_b128 -- EXACTLY the same LDS layout/swizzle as the
// previous async path (phys chunk l&7 holds logical chunk (l&7)^(row&7)),
// so all fragment reads are unchanged. B (Wt bf16) stays global_load_lds.
// grid (512, 1, 3), block 256: 4 waves, each 64x64 of the 128x128 tile.
// ---------------------------------------------------------------------------
__global__ __launch_bounds__(256) void proj_kernel(
    const float* __restrict__ Aq, const float* __restrict__ Ak,
    const float* __restrict__ Av, const bf16_t* __restrict__ Wt,
    bf16_t* __restrict__ qw, bf16_t* __restrict__ kw, bf16_t* __restrict__ vwt)
{
    const int which = blockIdx.z;
    const float* A = which == 0 ? Aq : which == 1 ? Ak : Av;
    const bf16_t* T = Wt + ((size_t)which << 20);

    __shared__ bf16_t Alds[128 * 64];  // [row][64k], 16B chunk c at c^(row&7)
    __shared__ bf16_t Blds[128 * 64];

    const int tid = threadIdx.x;
    const int lane = tid & 63;
    const int wave = tid >> 6;
    const int quad = lane >> 4;
    const int l16 = lane & 15;

    // XCD-locality decode: presumed placement XCD = blockIdx.x % 8
    const int id = blockIdx.x;
    const int xg = id & 7;
    const int sl = id >> 3;                   // 0..63
    const int m0 = (((xg << 3) | (sl >> 3))) * 128;  // XCD xg: m-panels xg*8..xg*8+7
    const int n0 = (sl & 7) * 128;

    const int wm = (wave >> 1) * 64;
    const int wn = (wave & 1) * 64;

    const int srow = lane >> 3;   // 8 rows per staging instr
    const int schk = lane & 7;    // physical 16B chunk

    f32x4 zero4 = {0.f, 0.f, 0.f, 0.f};
    f32x4 acc[4][4];
    #pragma unroll
    for (int i = 0; i < 4; i++)
        #pragma unroll
        for (int j = 0; j < 4; j++) acc[i][j] = zero4;

    for (int k0 = 0; k0 < DD; k0 += 64) {
        // B tile: async bf16 staging (unchanged)
        #pragma unroll
        for (int j = 0; j < 4; j++) {
            int r0 = wave * 32 + j * 8;
            int row = r0 + srow;
            int c = schk ^ (row & 7);
            async_copy16(&T[(size_t)(n0 + row) * 1024 + k0 + c * 8], &Blds[r0 * 64]);
        }
        // A tile: fp32 load + convert + lane-linear ds_write (fused conv)
        #pragma unroll
        for (int j = 0; j < 4; j++) {
            int r0 = wave * 32 + j * 8;
            int row = r0 + srow;
            int c = schk ^ (row & 7);
            const float* src = &A[(size_t)(m0 + row) * 1024 + k0 + c * 8];
            f32x4 a0 = *(const f32x4*)src;
            f32x4 a1 = *(const f32x4*)(src + 4);
            bf16x8 o;
            o[0] = (bf16_t)a0[0]; o[1] = (bf16_t)a0[1];
            o[2] = (bf16_t)a0[2]; o[3] = (bf16_t)a0[3];
            o[4] = (bf16_t)a1[0]; o[5] = (bf16_t)a1[1];
            o[6] = (bf16_t)a1[2]; o[7] = (bf16_t)a1[3];
            // phys chunk = schk; lane-linear 16B stride -> conflict-free
            *(bf16x8*)&Alds[row * 64 + schk * 8] = o;
        }
        __syncthreads();

        #pragma unroll
        for (int s = 0; s < 2; s++) {
            bf16x8 af[4], bfr[4];
            #pragma unroll
            for (int mi = 0; mi < 4; mi++)
                af[mi] = *(const bf16x8*)&Alds[(wm + mi * 16 + l16) * 64 +
                             (((s * 4 + quad) ^ (l16 & 7)) << 3)];
            #pragma unroll
            for (int ni = 0; ni < 4; ni++)
                bfr[ni] = *(const bf16x8*)&Blds[(wn + ni * 16 + l16) * 64 +
                              (((s * 4 + quad) ^ (l16 & 7)) << 3)];
            #pragma unroll
            for (int mi = 0; mi < 4; mi++)
                #pragma unroll
                for (int ni = 0; ni < 4; ni++)
                    acc[mi][ni] = MFMA16(af[mi], bfr[ni], acc[mi][ni]);
        }
        __syncthreads();
    }

    // C/D layout: col=lane&15, row=quad*4+reg
    if (which < 2) {
        bf16_t* Cout = which == 0 ? qw : kw;
        #pragma unroll
        for (int mi = 0; mi < 4; mi++)
            #pragma unroll
            for (int ni = 0; ni < 4; ni++)
                #pragma unroll
                for (int r = 0; r < 4; r++) {
                    int row = m0 + wm + mi * 16 + quad * 4 + r;
                    int col = n0 + wn + ni * 16 + l16;
                    Cout[(size_t)row * 1024 + col] = (bf16_t)acc[mi][ni][r];
                }
    } else {
        // vwt[b][h][d][s]; the 4 acc regs are s-consecutive -> bf16x4 stores
        #pragma unroll
        for (int mi = 0; mi < 4; mi++)
            #pragma unroll
            for (int ni = 0; ni < 4; ni++) {
                int s0 = m0 + wm + mi * 16 + quad * 4;
                int col = n0 + wn + ni * 16 + l16;
                int b = s0 >> 11, s = s0 & 2047;
                int h = col >> 6, d = col & 63;
                bf16x4 p;
                p[0] = (bf16_t)acc[mi][ni][0]; p[1] = (bf16_t)acc[mi][ni][1];
                p[2] = (bf16_t)acc[mi][ni][2]; p[3] = (bf16_t)acc[mi][ni][3];
                *(bf16x4*)&vwt[(((size_t)((b * HH + h) * DH + d)) << 11) + s] = p;
            }
    }
}

// ---------------------------------------------------------------------------
// flash attention, 32x32 swapped-operand form, no-rescale softmax.
// REVERTED VERBATIM to the round-2 kernel (116.4 us measured -- best of 7
// rounds; every structural change since regressed: 2-wave blocks 155,
// zero-barrier reg-staging 152, counted-vmcnt 169 -- all crossed the
// 128-VGPR occupancy cliff or serialized staging). Loop-invariant LDS/global
// pointers, t-loop unrolled by 2, setprio around MFMA clusters.
// grid (1024, 1, 1), block 256 (4 waves x 32 queries).
// ---------------------------------------------------------------------------
__global__ __launch_bounds__(256) void attn_kernel(
    const bf16_t* __restrict__ qw, const bf16_t* __restrict__ kw,
    const bf16_t* __restrict__ vwt, const float* __restrict__ v_mask,
    const float* __restrict__ q_mask, float* __restrict__ out)
{
    // XCD-locality decode
    const int linear = blockIdx.x;           // 0..1023
    const int xg = linear & 7;               // presumed XCD
    const int sl = linear >> 3;              // 0..127
    const int grp = (xg << 3) | (sl >> 4);   // 0..63: XCD xg gets groups xg*8..+7
    const int qt = sl & 15;
    const int b = grp >> 4;
    const int h = grp & 15;

    // flat KV: K[cur] at cur*4096 el, V[cur] at 8192 + cur*4096 el
    __shared__ __align__(16) bf16_t KV[4 * 4096];
    __shared__ float vml[2][64];             // (1-v_mask)*1e10*log2e

    const int tid = threadIdx.x;
    const int lane = tid & 63;
    const int wave = tid >> 6;
    const int l5 = lane & 31;
    const int hi = lane >> 5;
    const int q0 = qt * 128 + wave * 32;

    const int srow = lane >> 3;   // staging: 8 rows per instr
    const int schk = lane & 7;    // physical 16B chunk

    // Q fragments: B-operand, lane holds col=query(l5), k = d = c*16+hi*8..+7
    bf16x8 qf[4];
    #pragma unroll
    for (int c = 0; c < 4; ++c)
        qf[c] = *(const bf16x8*)&qw[(size_t)(b * SS + q0 + l5) * 1024 + h * 64 +
                                    c * 16 + hi * 8];

    f32x16 zero16;
    #pragma unroll
    for (int i = 0; i < 16; ++i) zero16[i] = 0.f;

    // loop-invariant LDS read pointers: chunk((2j+hi)^(l5&7)) = vkh^2j
    const int vkh = (l5 & 7) ^ hi;
    const bf16_t* pj[4];
    #pragma unroll
    for (int j = 0; j < 4; ++j)
        pj[j] = &KV[l5 * 64 + ((vkh ^ (2 * j)) << 3)];
    const float* vmlp = &vml[0][hi * 4];

    // persistent staging pointers (incremented by const stride per tile)
    const bf16_t* gk[2];
    const bf16_t* gv[2];
    #pragma unroll
    for (int j = 0; j < 2; ++j) {
        int row = (wave * 2 + j) * 8 + srow;
        int ck = schk ^ (row & 7);
        gk[j] = &kw[(size_t)(b * SS + row) * 1024 + h * 64 + ck * 8];
        gv[j] = &vwt[(((size_t)((b * HH + h) * DH + row)) << 11) + ck * 8];
    }
    const float* vmp = v_mask + b * SS + tid;

    auto stage = [&](int bi) {
        #pragma unroll
        for (int j = 0; j < 2; ++j) {
            async_copy16(gk[j], &KV[bi * 4096 + (wave * 2 + j) * 512]);
            gk[j] += 64 * 1024;
        }
        #pragma unroll
        for (int j = 0; j < 2; ++j) {
            async_copy16(gv[j], &KV[8192 + bi * 4096 + (wave * 2 + j) * 512]);
            gv[j] += 64;
        }
        if (tid < 64)
            vml[bi][tid] = (1.0f - *vmp) * 1.4426950408889634e10f;
        vmp += 64;
    };

    stage(0);
    __syncthreads();

    f32x16 o0 = zero16, o1 = zero16;   // O^T: rows d 0-31 / 32-63, col = query
    f32x4 l4 = {0.f, 0.f, 0.f, 0.f};   // 4 independent l-sum chains

    for (int t2 = 0; t2 < 32; t2 += 2) {
        #pragma unroll
        for (int cur = 0; cur < 2; ++cur) {
            if (t2 + cur + 1 < 32) stage(cur ^ 1);   // prefetch next tile

            // S^T = K @ Q^T: row = key, col = query(l5). Two 32-key blocks.
            __builtin_amdgcn_s_setprio(1);
            f32x16 st0, st1;
            {
                bf16x8 k0 = *(const bf16x8*)(pj[0] + cur * 4096);
                bf16x8 k1 = *(const bf16x8*)(pj[0] + cur * 4096 + 2048);
                st0 = MFMA32(k0, qf[0], zero16);
                st1 = MFMA32(k1, qf[0], zero16);
            }
            #pragma unroll
            for (int c = 1; c < 4; ++c) {
                bf16x8 k0 = *(const bf16x8*)(pj[c] + cur * 4096);
                bf16x8 k1 = *(const bf16x8*)(pj[c] + cur * 4096 + 2048);
                st0 = MFMA32(k0, qf[c], st0);
                st1 = MFMA32(k1, qf[c], st1);
            }
            __builtin_amdgcn_s_setprio(0);

            #pragma unroll
            for (int kb = 0; kb < 2; ++kb) {
                f32x16& st = kb ? st1 : st0;
                // softmax (no max, no rescale): p = exp2(s*C1 - vml[key])
                // key(reg r) = kb*32 + (r&3) + 8*(r>>2) + 4*hi
                #pragma unroll
                for (int g = 0; g < 4; ++g) {
                    f32x4 vm4 = *(const f32x4*)(vmlp + cur * 64 + kb * 32 + g * 8);
                    #pragma unroll
                    for (int j = 0; j < 4; ++j) {
                        float p = __builtin_amdgcn_exp2f(
                            __builtin_fmaf(st[g * 4 + j], C1, -vm4[j]));
                        st[g * 4 + j] = p;
                        l4[j] += p;
                    }
                }
                // pack P pairs and swap halves (T12 pairing)
                unsigned a0 = pack_bf16(st[0],  st[1]);
                unsigned a1 = pack_bf16(st[2],  st[3]);
                unsigned a2 = pack_bf16(st[4],  st[5]);
                unsigned a3 = pack_bf16(st[6],  st[7]);
                unsigned a4 = pack_bf16(st[8],  st[9]);
                unsigned a5 = pack_bf16(st[10], st[11]);
                unsigned a6 = pack_bf16(st[12], st[13]);
                unsigned a7 = pack_bf16(st[14], st[15]);
                permswap(a0, a2);
                permswap(a1, a3);
                permswap(a4, a6);
                permswap(a5, a7);
                u32x4 w0 = {a0, a1, a2, a3};   // keys kb*32 + [0,16)
                u32x4 w1 = {a4, a5, a6, a7};   // keys kb*32 + [16,32)
                bf16x8 bp0 = __builtin_bit_cast(bf16x8, w0);
                bf16x8 bp1 = __builtin_bit_cast(bf16x8, w1);

                // O^T += V^T @ P  (A = V^T rows d, k = key chunk of 16)
                __builtin_amdgcn_s_setprio(1);
                #pragma unroll
                for (int c = 0; c < 2; ++c) {
                    bf16x8 bp = c ? bp1 : bp0;
                    const bf16_t* pv = pj[kb * 2 + c] + 8192 + cur * 4096;
                    bf16x8 av0 = *(const bf16x8*)(pv);
                    bf16x8 av1 = *(const bf16x8*)(pv + 2048);
                    o0 = MFMA32(av0, bp, o0);
                    o1 = MFMA32(av1, bp, o1);
                }
                __builtin_amdgcn_s_setprio(0);
            }
            __syncthreads();   // next buffer staged; cur reads done
        }
    }

    // combine l partials: 4 chains, then the two lane-halves (hi) per query
    float l_i = (l4[0] + l4[1]) + (l4[2] + l4[3]);
    l_i += __shfl_xor(l_i, 32);

    const int q = q0 + l5;
    const float sc = q_mask[b * SS + q] / l_i;
    // O^T reg r: d = db*32 + (r&3) + 8*(r>>2) + 4*hi, col q = l5
    #pragma unroll
    for (int db = 0; db < 2; ++db) {
        const f32x16 oa = db ? o1 : o0;
        #pragma unroll
        for (int g = 0; g < 4; ++g) {
            f32x4 o4;
            o4[0] = oa[g * 4 + 0] * sc;
            o4[1] = oa[g * 4 + 1] * sc;
            o4[2] = oa[g * 4 + 2] * sc;
            o4[3] = oa[g * 4 + 3] * sc;
            *(f32x4*)&out[(size_t)(b * SS + q) * 1024 + h * 64 +
                          db * 32 + g * 8 + hi * 4] = o4;
        }
    }
}

// ---------------------------------------------------------------------------
extern "C" void kernel_launch(void* const* d_in, const int* in_sizes, int n_in,
                              void* d_out, int out_size, void* d_ws, size_t ws_size,
                              hipStream_t stream)
{
    const float* q  = (const float*)d_in[0];
    const float* k  = (const float*)d_in[1];
    const float* v  = (const float*)d_in[2];
    const float* vm = (const float*)d_in[3];
    const float* qm = (const float*)d_in[4];
    const float* Wq = (const float*)d_in[5];
    const float* Wk = (const float*)d_in[6];
    const float* Wv = (const float*)d_in[7];
    float* out = (float*)d_out;

    const size_t elems = (size_t)BB * SS * DD;  // 8388608
    bf16_t* qw  = (bf16_t*)d_ws;       // conv deleted: Ab no longer exists
    bf16_t* kw  = qw + elems;
    bf16_t* vwt = kw + elems;
    bf16_t* Wt  = vwt + elems;         // 3 x 1024 x 1024

    wtrans_kernel<<<dim3(16, 16, 3), 256, 0, stream>>>(Wq, Wk, Wv, Wt);
    proj_kernel<<<dim3(512, 1, 3), 256, 0, stream>>>(q, k, v, Wt, qw, kw, vwt);
    attn_kernel<<<dim3(1024, 1, 1), 256, 0, stream>>>(qw, kw, vwt, vm, qm, out);
}